// Round 5
// baseline (182.112 us; speedup 1.0000x reference)
//
#include <hip/hip_runtime.h>
#include <hip/hip_bf16.h>

#define NB 8
#define CC 256
#define CP 32
#define NN 4096
#define LOG2E 1.44269504088896340736f

typedef __attribute__((ext_vector_type(8))) short short8;
typedef __attribute__((ext_vector_type(4))) float floatx4;
typedef __attribute__((ext_vector_type(4))) int intx4;

static __device__ __forceinline__ ushort bf16r(float f) {
    __hip_bfloat16 h = __float2bfloat16(f);
    return *reinterpret_cast<ushort*>(&h);
}
static __device__ __forceinline__ float bf2f(ushort u) {
    union { unsigned int i; float f; } x;
    x.i = ((unsigned int)u) << 16;
    return x.f;
}
static __device__ __forceinline__ short8 load_frag(const ushort* p) {
    intx4 v = *reinterpret_cast<const intx4*>(p);
    return *reinterpret_cast<short8*>(&v);
}
// pack two f32 -> bf16x2, round-half-up, via v_perm (3 VALU ops)
static __device__ __forceinline__ unsigned int pk2(float a, float b) {
#if defined(__has_builtin) && __has_builtin(__builtin_amdgcn_perm)
    return __builtin_amdgcn_perm(__float_as_uint(b) + 0x8000u, __float_as_uint(a) + 0x8000u, 0x07060302u);
#else
    unsigned int ua = __float_as_uint(a) + 0x8000u;
    unsigned int ub = __float_as_uint(b) + 0x8000u;
    return (ua >> 16) | (ub & 0xFFFF0000u);
#endif
}
static __device__ __forceinline__ ushort pk1(float a) {
    return (ushort)((__float_as_uint(a) + 0x8000u) >> 16);
}
// 2^x via v_exp_f32 (inputs pre-scaled by log2e)
static __device__ __forceinline__ float fexp2(float x) {
#if defined(__has_builtin)
#if __has_builtin(__builtin_amdgcn_exp2f)
    return __builtin_amdgcn_exp2f(x);
#else
    return __expf(x * 0.69314718055994530942f);
#endif
#else
    return __expf(x * 0.69314718055994530942f);
#endif
}

// ---------------- Kernel 0: W prep. blocks 0..95: Wq/Wk/Wv -> W96 bf16 (Wq scaled by log2e).
// blocks 96..127: Wb -> W2b bf16 [256][32] flat. ----------------
__global__ void prep_w(const float* __restrict__ Wq, const float* __restrict__ Wk,
                       const float* __restrict__ Wv, const float* __restrict__ Wb,
                       ushort* __restrict__ W96, ushort* __restrict__ W2b) {
    int r = blockIdx.x, c = threadIdx.x;
    if (r < 96) {
        const float* src = (r < 32) ? (Wq + r * CC) : ((r < 64) ? (Wk + (r - 32) * CC) : (Wv + (r - 64) * CC));
        float scale = (r < 32) ? LOG2E : 1.0f;
        W96[r * CC + c] = bf16r(src[c] * scale);
    } else {
        int idx = (r - 96) * 256 + c;
        W2b[idx] = bf16r(Wb[idx]);
    }
}

// ---------------- Kernel 1: projection x -> Qt, Kt, Vt (all [b][n][32] bf16; Q pre-scaled by log2e) ----------------
__global__ __launch_bounds__(256) void proj_kernel(
    const float* __restrict__ x, const ushort* __restrict__ W96,
    const float* __restrict__ bq, const float* __restrict__ bk, const float* __restrict__ bv,
    ushort* __restrict__ Qt, ushort* __restrict__ Kt, ushort* __restrict__ Vt) {
    __shared__ ushort xt[64 * 264];  // [n_local][c], stride 264
    int b = blockIdx.x >> 6, nt = blockIdx.x & 63;
    int t = threadIdx.x;
    int n0 = nt * 64;
    {
        int cq = t >> 4, n4 = (t & 15) * 4;
#pragma unroll
        for (int cc = 0; cc < 4; cc++) {
            int c_base = cc * 64 + cq * 4;
            float4 xv[4];
#pragma unroll
            for (int e = 0; e < 4; e++)
                xv[e] = *reinterpret_cast<const float4*>(&x[((size_t)b * CC + c_base + e) * NN + n0 + n4]);
            const float* xs = reinterpret_cast<const float*>(xv);
#pragma unroll
            for (int jj = 0; jj < 4; jj++) {
                ushort4 u;
                u.x = pk1(xs[0 * 4 + jj]);
                u.y = pk1(xs[1 * 4 + jj]);
                u.z = pk1(xs[2 * 4 + jj]);
                u.w = pk1(xs[3 * 4 + jj]);
                *reinterpret_cast<ushort4*>(&xt[(n4 + jj) * 264 + c_base]) = u;
            }
        }
    }
    __syncthreads();
    int w = t >> 6, lane = t & 63, l15 = lane & 15, q = lane >> 4;
    floatx4 acc[6];
#pragma unroll
    for (int k = 0; k < 6; k++) acc[k] = (floatx4){0.f, 0.f, 0.f, 0.f};
#pragma unroll
    for (int ks = 0; ks < 8; ks++) {
        short8 bfrag = load_frag(&xt[(w * 16 + l15) * 264 + ks * 32 + q * 8]);
#pragma unroll
        for (int ot = 0; ot < 6; ot++) {
            short8 afrag = load_frag(&W96[(size_t)(ot * 16 + l15) * CC + ks * 32 + q * 8]);
            acc[ot] = __builtin_amdgcn_mfma_f32_16x16x32_bf16(afrag, bfrag, acc[ot], 0, 0, 0);
        }
    }
    int n = n0 + w * 16 + l15;
#pragma unroll
    for (int ot = 0; ot < 6; ot++) {
        const float* bias = (ot < 2) ? bq : ((ot < 4) ? bk : bv);
        ushort* dst = (ot < 2) ? Qt : ((ot < 4) ? Kt : Vt);
        int o0 = (ot & 1) * 16 + q * 4;
        float4 b4 = *reinterpret_cast<const float4*>(bias + o0);
        float sc = (ot < 2) ? LOG2E : 1.0f;
        ushort4 pk;
        pk.x = bf16r(acc[ot][0] + b4.x * sc);
        pk.y = bf16r(acc[ot][1] + b4.y * sc);
        pk.z = bf16r(acc[ot][2] + b4.z * sc);
        pk.w = bf16r(acc[ot][3] + b4.w * sc);
        *reinterpret_cast<ushort4*>(&dst[((size_t)b * NN + n) * CP + o0]) = pk;
    }
}

// ---------------- Kernel 2: pass A — partial row sums of 2^(S') over m-quarters ----------------
__global__ __launch_bounds__(256, 4) void passA_kernel(
    const ushort* __restrict__ Qt, const ushort* __restrict__ Kt, float* __restrict__ Fp) {
    __shared__ ushort kst[256 * 40];  // 20 KB, padded rows
    int bid = blockIdx.x;
    int mq = bid & 3, jt = (bid >> 2) & 63, b = bid >> 8;
    int w = threadIdx.x >> 6, lane = threadIdx.x & 63;
    int l15 = lane & 15, q = lane >> 4;
    int j = jt * 64 + w * 16 + l15;

    short8 af = load_frag(&Qt[((size_t)b * NN + j) * CP + q * 8]);
    floatx4 lacc = (floatx4){0.f, 0.f, 0.f, 0.f};

    for (int mc = 0; mc < 4; mc++) {
        int m0 = mq * 1024 + mc * 256;
        __syncthreads();
        {
            const intx4* src = reinterpret_cast<const intx4*>(&Kt[((size_t)b * NN + m0) * CP]);
            intx4* dst = reinterpret_cast<intx4*>(kst);
#pragma unroll
            for (int s = 0; s < 4; s++) {
                int g = threadIdx.x + 256 * s;
                dst[(g >> 2) * 5 + (g & 3)] = src[g];
            }
        }
        __syncthreads();
#pragma unroll
        for (int ms = 0; ms < 16; ms++) {
            short8 bf = load_frag(&kst[(ms * 16 + l15) * 40 + q * 8]);
            floatx4 z = (floatx4){0.f, 0.f, 0.f, 0.f};
            floatx4 s = __builtin_amdgcn_mfma_f32_16x16x32_bf16(af, bf, z, 0, 0, 0);
            lacc[0] += fexp2(s[0]);
            lacc[1] += fexp2(s[1]);
            lacc[2] += fexp2(s[2]);
            lacc[3] += fexp2(s[3]);
        }
    }
#pragma unroll
    for (int d = 1; d < 16; d <<= 1) {
        lacc[0] += __shfl_xor(lacc[0], d, 64);
        lacc[1] += __shfl_xor(lacc[1], d, 64);
        lacc[2] += __shfl_xor(lacc[2], d, 64);
        lacc[3] += __shfl_xor(lacc[3], d, 64);
    }
    if (l15 == 0) {
        float4 f4;
        f4.x = lacc[0]; f4.y = lacc[1]; f4.z = lacc[2]; f4.w = lacc[3];
        *reinterpret_cast<float4*>(&Fp[((size_t)mq * NB + b) * NN + jt * 64 + w * 16 + q * 4]) = f4;
    }
}

// ---------------- Kernel 3: combine Fp, fold into V, transpose -> Vp[b][32][n] bf16 ----------------
__global__ __launch_bounds__(256) void fold_kernel(
    const ushort* __restrict__ Vt, const float* __restrict__ Fp, ushort* __restrict__ Vp) {
    __shared__ ushort tile[32 * 136];
    const size_t PL = (size_t)NB * NN;
    int b = blockIdx.x >> 5, nc = blockIdx.x & 31;
    int t = threadIdx.x;
    int half = t >> 7, nl = t & 127;
    int n = nc * 128 + nl;
    size_t bn = (size_t)b * NN + n;
    float f = 1.0f / (Fp[bn] + Fp[PL + bn] + Fp[2 * PL + bn] + Fp[3 * PL + bn]);
    const ushort* src = &Vt[bn * CP + half * 16];
#pragma unroll
    for (int g = 0; g < 2; g++) {
        intx4 raw = *reinterpret_cast<const intx4*>(src + g * 8);
        const ushort* us = reinterpret_cast<const ushort*>(&raw);
#pragma unroll
        for (int e = 0; e < 8; e++) {
            tile[(half * 16 + g * 8 + e) * 136 + nl] = pk1(bf2f(us[e]) * f);
        }
    }
    __syncthreads();
#pragma unroll
    for (int cc = 0; cc < 16; cc++) {
        int c = half * 16 + cc;
        Vp[((size_t)b * CP + c) * NN + nc * 128 + nl] = tile[c * 136 + nl];
    }
}

// ---------------- Kernel 4: pass B — O[32c][32i] over all j, NO LDS staging / NO K-loop barriers.
// grid 1024 = b(8) x it(128). 4 waves split j 4-way (independent streams, direct global frag loads);
// partials merged in LDS, fused MFMA back-proj + bias + residual. ----------------
__global__ __launch_bounds__(256, 6) void passB_kernel(
    const ushort* __restrict__ Qt, const ushort* __restrict__ Kt, const ushort* __restrict__ Vp,
    const ushort* __restrict__ W2b, const float* __restrict__ bb, const float* __restrict__ x,
    float* __restrict__ out) {
    __shared__ float olds4[4 * 32 * 33];  // 16.9 KB: per-wave partial O tiles

    int bid = blockIdx.x;
    int it = bid & 127, b = bid >> 7;
    int w = threadIdx.x >> 6, lane = threadIdx.x & 63;
    int l15 = lane & 15, q = lane >> 4;
    int i0 = it * 32;

    short8 kf0 = load_frag(&Kt[((size_t)b * NN + i0 + l15) * CP + q * 8]);
    short8 kf1 = load_frag(&Kt[((size_t)b * NN + i0 + 16 + l15) * CP + q * 8]);

    floatx4 acc00 = (floatx4){0.f, 0.f, 0.f, 0.f};  // c 0-15  x i 0-15
    floatx4 acc10 = (floatx4){0.f, 0.f, 0.f, 0.f};  // c 16-31 x i 0-15
    floatx4 acc01 = (floatx4){0.f, 0.f, 0.f, 0.f};  // c 0-15  x i 16-31
    floatx4 acc11 = (floatx4){0.f, 0.f, 0.f, 0.f};  // c 16-31 x i 16-31

    int qrow = (l15 >> 2) * 8 + (l15 & 3);  // perm: C-layout of S == B-frag layout of PV
    const ushort* qbase = Qt + ((size_t)b * NN + qrow) * CP + q * 8;
    const ushort* vbase0 = Vp + ((size_t)b * CP + l15) * NN + q * 8;
    const ushort* vbase1 = Vp + ((size_t)b * CP + 16 + l15) * NN + q * 8;

#pragma unroll 2
    for (int jb = w; jb < 128; jb += 4) {
        int j0 = jb * 32;
        short8 a0 = load_frag(qbase + (size_t)j0 * CP);
        short8 a1 = load_frag(qbase + (size_t)(j0 + 4) * CP);
        short8 va0 = load_frag(vbase0 + j0);
        short8 va1 = load_frag(vbase1 + j0);

        floatx4 z = (floatx4){0.f, 0.f, 0.f, 0.f};
        floatx4 s0A = __builtin_amdgcn_mfma_f32_16x16x32_bf16(a0, kf0, z, 0, 0, 0);
        floatx4 s1A = __builtin_amdgcn_mfma_f32_16x16x32_bf16(a1, kf0, z, 0, 0, 0);
        floatx4 s0B = __builtin_amdgcn_mfma_f32_16x16x32_bf16(a0, kf1, z, 0, 0, 0);
        floatx4 s1B = __builtin_amdgcn_mfma_f32_16x16x32_bf16(a1, kf1, z, 0, 0, 0);

        union { intx4 v; short8 s; } wa, wb2;
        wa.v.x = pk2(fexp2(s0A[0]), fexp2(s0A[1]));
        wa.v.y = pk2(fexp2(s0A[2]), fexp2(s0A[3]));
        wa.v.z = pk2(fexp2(s1A[0]), fexp2(s1A[1]));
        wa.v.w = pk2(fexp2(s1A[2]), fexp2(s1A[3]));
        wb2.v.x = pk2(fexp2(s0B[0]), fexp2(s0B[1]));
        wb2.v.y = pk2(fexp2(s0B[2]), fexp2(s0B[3]));
        wb2.v.z = pk2(fexp2(s1B[0]), fexp2(s1B[1]));
        wb2.v.w = pk2(fexp2(s1B[2]), fexp2(s1B[3]));

        acc00 = __builtin_amdgcn_mfma_f32_16x16x32_bf16(va0, wa.s, acc00, 0, 0, 0);
        acc10 = __builtin_amdgcn_mfma_f32_16x16x32_bf16(va1, wa.s, acc10, 0, 0, 0);
        acc01 = __builtin_amdgcn_mfma_f32_16x16x32_bf16(va0, wb2.s, acc01, 0, 0, 0);
        acc11 = __builtin_amdgcn_mfma_f32_16x16x32_bf16(va1, wb2.s, acc11, 0, 0, 0);
    }

    // ---- merge 4 wave partials via LDS: olds4[w][32 c][33] ----
    int mbase = w * (32 * 33);
#pragma unroll
    for (int r = 0; r < 4; r++) {
        olds4[mbase + (q * 4 + r) * 33 + l15] = acc00[r];
        olds4[mbase + (16 + q * 4 + r) * 33 + l15] = acc10[r];
        olds4[mbase + (q * 4 + r) * 33 + 16 + l15] = acc01[r];
        olds4[mbase + (16 + q * 4 + r) * 33 + 16 + l15] = acc11[r];
    }
    __syncthreads();

    // ---- epilogue: back[c,i] = Wb.O + bb + x ; wave w handles c in [w*64, w*64+64) ----
    short8 bfr[2];
#pragma unroll
    for (int s = 0; s < 2; s++) {
        float o8[8];
#pragma unroll
        for (int jj = 0; jj < 8; jj++) {
            int o = q * 8 + jj;
            int idx = o * 33 + s * 16 + l15;
            o8[jj] = olds4[idx] + olds4[1056 + idx] + olds4[2112 + idx] + olds4[3168 + idx];
        }
        union { intx4 v; short8 sh; } u;
        u.v.x = pk2(o8[0], o8[1]);
        u.v.y = pk2(o8[2], o8[3]);
        u.v.z = pk2(o8[4], o8[5]);
        u.v.w = pk2(o8[6], o8[7]);
        bfr[s] = u.sh;
    }
    int c0 = w * 64;
#pragma unroll
    for (int cs = 0; cs < 4; cs++) {
        short8 af = load_frag(&W2b[(size_t)(c0 + cs * 16 + l15) * CP + q * 8]);
#pragma unroll
        for (int s = 0; s < 2; s++) {
            floatx4 z = (floatx4){0.f, 0.f, 0.f, 0.f};
            floatx4 d = __builtin_amdgcn_mfma_f32_16x16x32_bf16(af, bfr[s], z, 0, 0, 0);
#pragma unroll
            for (int r = 0; r < 4; r++) {
                int c = c0 + cs * 16 + q * 4 + r;
                int i = i0 + s * 16 + l15;
                size_t idx = ((size_t)b * CC + c) * NN + i;
                out[idx] = d[r] + bb[c] + x[idx];
            }
        }
    }
}

extern "C" void kernel_launch(void* const* d_in, const int* in_sizes, int n_in,
                              void* d_out, int out_size, void* d_ws, size_t ws_size,
                              hipStream_t stream) {
    const float* x  = (const float*)d_in[0];
    const float* Wq = (const float*)d_in[1];
    const float* bq = (const float*)d_in[2];
    const float* Wk = (const float*)d_in[3];
    const float* bk = (const float*)d_in[4];
    const float* Wv = (const float*)d_in[5];
    const float* bv = (const float*)d_in[6];
    const float* Wb = (const float*)d_in[7];
    const float* bb = (const float*)d_in[8];
    float* out = (float*)d_out;

    char* ws = (char*)d_ws;
    ushort* Qt  = (ushort*)(ws);                                   // 0..2MB
    ushort* Kt  = (ushort*)(ws + (2u << 20));                      // 2..4MB
    ushort* Vp  = (ushort*)(ws + (4u << 20));                      // 4..6MB
    ushort* Vt  = (ushort*)(ws + (6u << 20));                      // 6..8MB
    float*  Fp  = (float*) (ws + (8u << 20));                      // 8..8.5MB
    ushort* W96 = (ushort*)(ws + (8u << 20) + (1u << 19));         // 48KB
    ushort* W2b = (ushort*)(ws + (8u << 20) + (1u << 19) + (48u << 10));  // 16KB

    prep_w<<<128, 256, 0, stream>>>(Wq, Wk, Wv, Wb, W96, W2b);
    proj_kernel<<<512, 256, 0, stream>>>(x, W96, bq, bk, bv, Qt, Kt, Vt);
    passA_kernel<<<2048, 256, 0, stream>>>(Qt, Kt, Fp);
    fold_kernel<<<256, 256, 0, stream>>>(Vt, Fp, Vp);
    passB_kernel<<<1024, 256, 0, stream>>>(Qt, Kt, Vp, W2b, bb, x, out);
}

// Round 6
// 180.276 us; speedup vs baseline: 1.0102x; 1.0102x over previous
//
#include <hip/hip_runtime.h>
#include <hip/hip_bf16.h>

#define NB 8
#define CC 256
#define CP 32
#define NN 4096
#define LOG2E 1.44269504088896340736f

typedef __attribute__((ext_vector_type(8))) short short8;
typedef __attribute__((ext_vector_type(4))) float floatx4;
typedef __attribute__((ext_vector_type(4))) int intx4;

static __device__ __forceinline__ ushort bf16r(float f) {
    __hip_bfloat16 h = __float2bfloat16(f);
    return *reinterpret_cast<ushort*>(&h);
}
static __device__ __forceinline__ float bf2f(ushort u) {
    union { unsigned int i; float f; } x;
    x.i = ((unsigned int)u) << 16;
    return x.f;
}
static __device__ __forceinline__ short8 load_frag(const ushort* p) {
    intx4 v = *reinterpret_cast<const intx4*>(p);
    return *reinterpret_cast<short8*>(&v);
}
// pack two f32 -> bf16x2, round-half-up, via v_perm (3 VALU ops)
static __device__ __forceinline__ unsigned int pk2(float a, float b) {
#if defined(__has_builtin) && __has_builtin(__builtin_amdgcn_perm)
    return __builtin_amdgcn_perm(__float_as_uint(b) + 0x8000u, __float_as_uint(a) + 0x8000u, 0x07060302u);
#else
    unsigned int ua = __float_as_uint(a) + 0x8000u;
    unsigned int ub = __float_as_uint(b) + 0x8000u;
    return (ua >> 16) | (ub & 0xFFFF0000u);
#endif
}
static __device__ __forceinline__ ushort pk1(float a) {
    return (ushort)((__float_as_uint(a) + 0x8000u) >> 16);
}
// 2^x via v_exp_f32 (inputs pre-scaled by log2e)
static __device__ __forceinline__ float fexp2(float x) {
#if defined(__has_builtin)
#if __has_builtin(__builtin_amdgcn_exp2f)
    return __builtin_amdgcn_exp2f(x);
#else
    return __expf(x * 0.69314718055994530942f);
#endif
#else
    return __expf(x * 0.69314718055994530942f);
#endif
}

// ---------------- Kernel 0: W prep ----------------
__global__ void prep_w(const float* __restrict__ Wq, const float* __restrict__ Wk,
                       const float* __restrict__ Wv, const float* __restrict__ Wb,
                       ushort* __restrict__ W96, ushort* __restrict__ W2b) {
    int r = blockIdx.x, c = threadIdx.x;
    if (r < 96) {
        const float* src = (r < 32) ? (Wq + r * CC) : ((r < 64) ? (Wk + (r - 32) * CC) : (Wv + (r - 64) * CC));
        float scale = (r < 32) ? LOG2E : 1.0f;
        W96[r * CC + c] = bf16r(src[c] * scale);
    } else {
        int idx = (r - 96) * 256 + c;
        W2b[idx] = bf16r(Wb[idx]);
    }
}

// ---------------- Kernel 1: projection x -> Qt, Kt, Vt (all [b][n][32] bf16; Q pre-scaled by log2e) ----------------
__global__ __launch_bounds__(256) void proj_kernel(
    const float* __restrict__ x, const ushort* __restrict__ W96,
    const float* __restrict__ bq, const float* __restrict__ bk, const float* __restrict__ bv,
    ushort* __restrict__ Qt, ushort* __restrict__ Kt, ushort* __restrict__ Vt) {
    __shared__ ushort xt[64 * 264];  // [n_local][c], stride 264
    int b = blockIdx.x >> 6, nt = blockIdx.x & 63;
    int t = threadIdx.x;
    int n0 = nt * 64;
    {
        int cq = t >> 4, n4 = (t & 15) * 4;
#pragma unroll
        for (int cc = 0; cc < 4; cc++) {
            int c_base = cc * 64 + cq * 4;
            float4 xv[4];
#pragma unroll
            for (int e = 0; e < 4; e++)
                xv[e] = *reinterpret_cast<const float4*>(&x[((size_t)b * CC + c_base + e) * NN + n0 + n4]);
            const float* xs = reinterpret_cast<const float*>(xv);
#pragma unroll
            for (int jj = 0; jj < 4; jj++) {
                ushort4 u;
                u.x = pk1(xs[0 * 4 + jj]);
                u.y = pk1(xs[1 * 4 + jj]);
                u.z = pk1(xs[2 * 4 + jj]);
                u.w = pk1(xs[3 * 4 + jj]);
                *reinterpret_cast<ushort4*>(&xt[(n4 + jj) * 264 + c_base]) = u;
            }
        }
    }
    __syncthreads();
    int w = t >> 6, lane = t & 63, l15 = lane & 15, q = lane >> 4;
    floatx4 acc[6];
#pragma unroll
    for (int k = 0; k < 6; k++) acc[k] = (floatx4){0.f, 0.f, 0.f, 0.f};
#pragma unroll
    for (int ks = 0; ks < 8; ks++) {
        short8 bfrag = load_frag(&xt[(w * 16 + l15) * 264 + ks * 32 + q * 8]);
#pragma unroll
        for (int ot = 0; ot < 6; ot++) {
            short8 afrag = load_frag(&W96[(size_t)(ot * 16 + l15) * CC + ks * 32 + q * 8]);
            acc[ot] = __builtin_amdgcn_mfma_f32_16x16x32_bf16(afrag, bfrag, acc[ot], 0, 0, 0);
        }
    }
    int n = n0 + w * 16 + l15;
#pragma unroll
    for (int ot = 0; ot < 6; ot++) {
        const float* bias = (ot < 2) ? bq : ((ot < 4) ? bk : bv);
        ushort* dst = (ot < 2) ? Qt : ((ot < 4) ? Kt : Vt);
        int o0 = (ot & 1) * 16 + q * 4;
        float4 b4 = *reinterpret_cast<const float4*>(bias + o0);
        float sc = (ot < 2) ? LOG2E : 1.0f;
        ushort4 pk;
        pk.x = bf16r(acc[ot][0] + b4.x * sc);
        pk.y = bf16r(acc[ot][1] + b4.y * sc);
        pk.z = bf16r(acc[ot][2] + b4.z * sc);
        pk.w = bf16r(acc[ot][3] + b4.w * sc);
        *reinterpret_cast<ushort4*>(&dst[((size_t)b * NN + n) * CP + o0]) = pk;
    }
}

// ---------------- Kernel 2: pass A — partial row sums of 2^(S') over m-quarters.
// grid 2048 = ((b*64 + jt)*4 + mq). Block covers 64 j; each wave covers ALL 64 j over its
// private 256-m sub-quarter (no cross-wave sharing -> no K-loop barriers), register-rotated
// K-fragment prefetch; cross-wave merge via tiny LDS. ----------------
__global__ __launch_bounds__(256, 6) void passA_kernel(
    const ushort* __restrict__ Qt, const ushort* __restrict__ Kt, float* __restrict__ Fp) {
    __shared__ float red[4][64];
    int bid = blockIdx.x;
    int mq = bid & 3, jt = (bid >> 2) & 63, b = bid >> 8;
    int w = threadIdx.x >> 6, lane = threadIdx.x & 63;
    int l15 = lane & 15, q = lane >> 4;

    short8 af[4];
#pragma unroll
    for (int js = 0; js < 4; js++)
        af[js] = load_frag(&Qt[((size_t)b * NN + jt * 64 + js * 16 + l15) * CP + q * 8]);

    floatx4 lacc[4];
#pragma unroll
    for (int js = 0; js < 4; js++) lacc[js] = (floatx4){0.f, 0.f, 0.f, 0.f};

    const ushort* kbase = Kt + ((size_t)b * NN + mq * 1024 + w * 256 + l15) * CP + q * 8;
    short8 bfc = load_frag(kbase);

#pragma unroll 2
    for (int ms = 0; ms < 16; ms++) {
        int mn = (ms + 1) & 15;
        short8 bfn = load_frag(kbase + (size_t)(mn * 16) * CP);
        floatx4 z = (floatx4){0.f, 0.f, 0.f, 0.f};
#pragma unroll
        for (int js = 0; js < 4; js++) {
            floatx4 s = __builtin_amdgcn_mfma_f32_16x16x32_bf16(af[js], bfc, z, 0, 0, 0);
            lacc[js][0] += fexp2(s[0]);
            lacc[js][1] += fexp2(s[1]);
            lacc[js][2] += fexp2(s[2]);
            lacc[js][3] += fexp2(s[3]);
        }
        bfc = bfn;
    }
    // reduce the 16 m-columns (l15 dim) within each quad-group
#pragma unroll
    for (int js = 0; js < 4; js++) {
#pragma unroll
        for (int d = 1; d < 16; d <<= 1) {
            lacc[js][0] += __shfl_xor(lacc[js][0], d, 64);
            lacc[js][1] += __shfl_xor(lacc[js][1], d, 64);
            lacc[js][2] += __shfl_xor(lacc[js][2], d, 64);
            lacc[js][3] += __shfl_xor(lacc[js][3], d, 64);
        }
    }
    if (l15 == 0) {
#pragma unroll
        for (int js = 0; js < 4; js++) {
#pragma unroll
            for (int r = 0; r < 4; r++) red[w][js * 16 + q * 4 + r] = lacc[js][r];
        }
    }
    __syncthreads();
    int t = threadIdx.x;
    if (t < 64) {
        float s = red[0][t] + red[1][t] + red[2][t] + red[3][t];
        Fp[((size_t)mq * NB + b) * NN + jt * 64 + t] = s;
    }
}

// ---------------- Kernel 3: combine Fp, fold into V, transpose -> Vp[b][32][n] bf16 ----------------
__global__ __launch_bounds__(256) void fold_kernel(
    const ushort* __restrict__ Vt, const float* __restrict__ Fp, ushort* __restrict__ Vp) {
    __shared__ ushort tile[32 * 136];
    const size_t PL = (size_t)NB * NN;
    int b = blockIdx.x >> 5, nc = blockIdx.x & 31;
    int t = threadIdx.x;
    int half = t >> 7, nl = t & 127;
    int n = nc * 128 + nl;
    size_t bn = (size_t)b * NN + n;
    float f = 1.0f / (Fp[bn] + Fp[PL + bn] + Fp[2 * PL + bn] + Fp[3 * PL + bn]);
    const ushort* src = &Vt[bn * CP + half * 16];
#pragma unroll
    for (int g = 0; g < 2; g++) {
        intx4 raw = *reinterpret_cast<const intx4*>(src + g * 8);
        const ushort* us = reinterpret_cast<const ushort*>(&raw);
#pragma unroll
        for (int e = 0; e < 8; e++) {
            tile[(half * 16 + g * 8 + e) * 136 + nl] = pk1(bf2f(us[e]) * f);
        }
    }
    __syncthreads();
#pragma unroll
    for (int cc = 0; cc < 16; cc++) {
        int c = half * 16 + cc;
        Vp[((size_t)b * CP + c) * NN + nc * 128 + nl] = tile[c * 136 + nl];
    }
}

// ---------------- Kernel 4: pass B — O[32c][32i] over all j; direct global frag loads with
// explicit register-rotation prefetch (no K-loop barriers); partials merged in LDS; fused
// MFMA back-proj + bias + residual. grid 1024 = b(8) x it(128). ----------------
__global__ __launch_bounds__(256, 4) void passB_kernel(
    const ushort* __restrict__ Qt, const ushort* __restrict__ Kt, const ushort* __restrict__ Vp,
    const ushort* __restrict__ W2b, const float* __restrict__ bb, const float* __restrict__ x,
    float* __restrict__ out) {
    __shared__ float olds4[4 * 32 * 33];  // 16.9 KB: per-wave partial O tiles

    int bid = blockIdx.x;
    int it = bid & 127, b = bid >> 7;
    int w = threadIdx.x >> 6, lane = threadIdx.x & 63;
    int l15 = lane & 15, q = lane >> 4;
    int i0 = it * 32;

    short8 kf0 = load_frag(&Kt[((size_t)b * NN + i0 + l15) * CP + q * 8]);
    short8 kf1 = load_frag(&Kt[((size_t)b * NN + i0 + 16 + l15) * CP + q * 8]);

    floatx4 acc00 = (floatx4){0.f, 0.f, 0.f, 0.f};  // c 0-15  x i 0-15
    floatx4 acc10 = (floatx4){0.f, 0.f, 0.f, 0.f};  // c 16-31 x i 0-15
    floatx4 acc01 = (floatx4){0.f, 0.f, 0.f, 0.f};  // c 0-15  x i 16-31
    floatx4 acc11 = (floatx4){0.f, 0.f, 0.f, 0.f};  // c 16-31 x i 16-31

    int qrow = (l15 >> 2) * 8 + (l15 & 3);  // perm: C-layout of S == B-frag layout of PV
    const ushort* qbase = Qt + ((size_t)b * NN + qrow) * CP + q * 8;
    const ushort* vbase0 = Vp + ((size_t)b * CP + l15) * NN + q * 8;
    const ushort* vbase1 = Vp + ((size_t)b * CP + 16 + l15) * NN + q * 8;

    // preload first fragment set
    int jf = w * 32;
    short8 a0c = load_frag(qbase + (size_t)jf * CP);
    short8 a1c = load_frag(qbase + (size_t)(jf + 4) * CP);
    short8 va0c = load_frag(vbase0 + jf);
    short8 va1c = load_frag(vbase1 + jf);

#pragma unroll 2
    for (int jb = w; jb < 128; jb += 4) {
        int jn0 = ((jb + 4) & 127) * 32;  // wrapped prefetch (last iter loads unused, in-bounds)
        short8 a0n = load_frag(qbase + (size_t)jn0 * CP);
        short8 a1n = load_frag(qbase + (size_t)(jn0 + 4) * CP);
        short8 va0n = load_frag(vbase0 + jn0);
        short8 va1n = load_frag(vbase1 + jn0);

        floatx4 z = (floatx4){0.f, 0.f, 0.f, 0.f};
        floatx4 s0A = __builtin_amdgcn_mfma_f32_16x16x32_bf16(a0c, kf0, z, 0, 0, 0);
        floatx4 s1A = __builtin_amdgcn_mfma_f32_16x16x32_bf16(a1c, kf0, z, 0, 0, 0);
        floatx4 s0B = __builtin_amdgcn_mfma_f32_16x16x32_bf16(a0c, kf1, z, 0, 0, 0);
        floatx4 s1B = __builtin_amdgcn_mfma_f32_16x16x32_bf16(a1c, kf1, z, 0, 0, 0);

        union { intx4 v; short8 s; } wa, wb2;
        wa.v.x = pk2(fexp2(s0A[0]), fexp2(s0A[1]));
        wa.v.y = pk2(fexp2(s0A[2]), fexp2(s0A[3]));
        wa.v.z = pk2(fexp2(s1A[0]), fexp2(s1A[1]));
        wa.v.w = pk2(fexp2(s1A[2]), fexp2(s1A[3]));
        wb2.v.x = pk2(fexp2(s0B[0]), fexp2(s0B[1]));
        wb2.v.y = pk2(fexp2(s0B[2]), fexp2(s0B[3]));
        wb2.v.z = pk2(fexp2(s1B[0]), fexp2(s1B[1]));
        wb2.v.w = pk2(fexp2(s1B[2]), fexp2(s1B[3]));

        acc00 = __builtin_amdgcn_mfma_f32_16x16x32_bf16(va0c, wa.s, acc00, 0, 0, 0);
        acc10 = __builtin_amdgcn_mfma_f32_16x16x32_bf16(va1c, wa.s, acc10, 0, 0, 0);
        acc01 = __builtin_amdgcn_mfma_f32_16x16x32_bf16(va0c, wb2.s, acc01, 0, 0, 0);
        acc11 = __builtin_amdgcn_mfma_f32_16x16x32_bf16(va1c, wb2.s, acc11, 0, 0, 0);

        a0c = a0n; a1c = a1n; va0c = va0n; va1c = va1n;
    }

    // ---- merge 4 wave partials via LDS: olds4[w][32 c][33] ----
    int mbase = w * (32 * 33);
#pragma unroll
    for (int r = 0; r < 4; r++) {
        olds4[mbase + (q * 4 + r) * 33 + l15] = acc00[r];
        olds4[mbase + (16 + q * 4 + r) * 33 + l15] = acc10[r];
        olds4[mbase + (q * 4 + r) * 33 + 16 + l15] = acc01[r];
        olds4[mbase + (16 + q * 4 + r) * 33 + 16 + l15] = acc11[r];
    }
    __syncthreads();

    // ---- epilogue: back[c,i] = Wb.O + bb + x ; wave w handles c in [w*64, w*64+64) ----
    short8 bfr[2];
#pragma unroll
    for (int s = 0; s < 2; s++) {
        float o8[8];
#pragma unroll
        for (int jj = 0; jj < 8; jj++) {
            int o = q * 8 + jj;
            int idx = o * 33 + s * 16 + l15;
            o8[jj] = olds4[idx] + olds4[1056 + idx] + olds4[2112 + idx] + olds4[3168 + idx];
        }
        union { intx4 v; short8 sh; } u;
        u.v.x = pk2(o8[0], o8[1]);
        u.v.y = pk2(o8[2], o8[3]);
        u.v.z = pk2(o8[4], o8[5]);
        u.v.w = pk2(o8[6], o8[7]);
        bfr[s] = u.sh;
    }
    int c0 = w * 64;
#pragma unroll
    for (int cs = 0; cs < 4; cs++) {
        short8 af = load_frag(&W2b[(size_t)(c0 + cs * 16 + l15) * CP + q * 8]);
#pragma unroll
        for (int s = 0; s < 2; s++) {
            floatx4 z = (floatx4){0.f, 0.f, 0.f, 0.f};
            floatx4 d = __builtin_amdgcn_mfma_f32_16x16x32_bf16(af, bfr[s], z, 0, 0, 0);
#pragma unroll
            for (int r = 0; r < 4; r++) {
                int c = c0 + cs * 16 + q * 4 + r;
                int i = i0 + s * 16 + l15;
                size_t idx = ((size_t)b * CC + c) * NN + i;
                out[idx] = d[r] + bb[c] + x[idx];
            }
        }
    }
}

extern "C" void kernel_launch(void* const* d_in, const int* in_sizes, int n_in,
                              void* d_out, int out_size, void* d_ws, size_t ws_size,
                              hipStream_t stream) {
    const float* x  = (const float*)d_in[0];
    const float* Wq = (const float*)d_in[1];
    const float* bq = (const float*)d_in[2];
    const float* Wk = (const float*)d_in[3];
    const float* bk = (const float*)d_in[4];
    const float* Wv = (const float*)d_in[5];
    const float* bv = (const float*)d_in[6];
    const float* Wb = (const float*)d_in[7];
    const float* bb = (const float*)d_in[8];
    float* out = (float*)d_out;

    char* ws = (char*)d_ws;
    ushort* Qt  = (ushort*)(ws);                                   // 0..2MB
    ushort* Kt  = (ushort*)(ws + (2u << 20));                      // 2..4MB
    ushort* Vp  = (ushort*)(ws + (4u << 20));                      // 4..6MB
    ushort* Vt  = (ushort*)(ws + (6u << 20));                      // 6..8MB
    float*  Fp  = (float*) (ws + (8u << 20));                      // 8..8.5MB
    ushort* W96 = (ushort*)(ws + (8u << 20) + (1u << 19));         // 48KB
    ushort* W2b = (ushort*)(ws + (8u << 20) + (1u << 19) + (48u << 10));  // 16KB

    prep_w<<<128, 256, 0, stream>>>(Wq, Wk, Wv, Wb, W96, W2b);
    proj_kernel<<<512, 256, 0, stream>>>(x, W96, bq, bk, bv, Qt, Kt, Vt);
    passA_kernel<<<2048, 256, 0, stream>>>(Qt, Kt, Fp);
    fold_kernel<<<256, 256, 0, stream>>>(Vt, Fp, Vp);
    passB_kernel<<<1024, 256, 0, stream>>>(Qt, Kt, Vp, W2b, bb, x, out);
}

// Round 7
// 163.357 us; speedup vs baseline: 1.1148x; 1.1036x over previous
//
#include <hip/hip_runtime.h>
#include <hip/hip_bf16.h>

#define NB 8
#define CC 256
#define CP 32
#define NN 4096
#define LOG2E 1.44269504088896340736f

typedef __attribute__((ext_vector_type(8))) short short8;
typedef __attribute__((ext_vector_type(4))) float floatx4;
typedef __attribute__((ext_vector_type(4))) int intx4;

static __device__ __forceinline__ ushort bf16r(float f) {
    __hip_bfloat16 h = __float2bfloat16(f);
    return *reinterpret_cast<ushort*>(&h);
}
static __device__ __forceinline__ float bf2f(ushort u) {
    union { unsigned int i; float f; } x;
    x.i = ((unsigned int)u) << 16;
    return x.f;
}
static __device__ __forceinline__ short8 load_frag(const ushort* p) {
    intx4 v = *reinterpret_cast<const intx4*>(p);
    return *reinterpret_cast<short8*>(&v);
}
static __device__ __forceinline__ unsigned int pk2(float a, float b) {
#if defined(__has_builtin) && __has_builtin(__builtin_amdgcn_perm)
    return __builtin_amdgcn_perm(__float_as_uint(b) + 0x8000u, __float_as_uint(a) + 0x8000u, 0x07060302u);
#else
    unsigned int ua = __float_as_uint(a) + 0x8000u;
    unsigned int ub = __float_as_uint(b) + 0x8000u;
    return (ua >> 16) | (ub & 0xFFFF0000u);
#endif
}
static __device__ __forceinline__ ushort pk1(float a) {
    return (ushort)((__float_as_uint(a) + 0x8000u) >> 16);
}
static __device__ __forceinline__ float fexp2(float x) {
#if defined(__has_builtin)
#if __has_builtin(__builtin_amdgcn_exp2f)
    return __builtin_amdgcn_exp2f(x);
#else
    return __expf(x * 0.69314718055994530942f);
#endif
#else
    return __expf(x * 0.69314718055994530942f);
#endif
}

// ---------------- Kernel 0: W prep ----------------
__global__ void prep_w(const float* __restrict__ Wq, const float* __restrict__ Wk,
                       const float* __restrict__ Wv, const float* __restrict__ Wb,
                       ushort* __restrict__ W96, ushort* __restrict__ W2b) {
    int r = blockIdx.x, c = threadIdx.x;
    if (r < 96) {
        const float* src = (r < 32) ? (Wq + r * CC) : ((r < 64) ? (Wk + (r - 32) * CC) : (Wv + (r - 64) * CC));
        float scale = (r < 32) ? LOG2E : 1.0f;
        W96[r * CC + c] = bf16r(src[c] * scale);
    } else {
        int idx = (r - 96) * 256 + c;
        W2b[idx] = bf16r(Wb[idx]);
    }
}

// ---------------- Kernel 1: projection x -> Qt, Kt ([b][n][32]) and Vp ([b][32][n], transposed) ----------------
__global__ __launch_bounds__(256) void proj_kernel(
    const float* __restrict__ x, const ushort* __restrict__ W96,
    const float* __restrict__ bq, const float* __restrict__ bk, const float* __restrict__ bv,
    ushort* __restrict__ Qt, ushort* __restrict__ Kt, ushort* __restrict__ Vp) {
    __shared__ ushort xt[64 * 264];  // [n_local][c], stride 264
    int b = blockIdx.x >> 6, nt = blockIdx.x & 63;
    int t = threadIdx.x;
    int n0 = nt * 64;
    {
        int cq = t >> 4, n4 = (t & 15) * 4;
#pragma unroll
        for (int cc = 0; cc < 4; cc++) {
            int c_base = cc * 64 + cq * 4;
            float4 xv[4];
#pragma unroll
            for (int e = 0; e < 4; e++)
                xv[e] = *reinterpret_cast<const float4*>(&x[((size_t)b * CC + c_base + e) * NN + n0 + n4]);
            const float* xs = reinterpret_cast<const float*>(xv);
#pragma unroll
            for (int jj = 0; jj < 4; jj++) {
                ushort4 u;
                u.x = pk1(xs[0 * 4 + jj]);
                u.y = pk1(xs[1 * 4 + jj]);
                u.z = pk1(xs[2 * 4 + jj]);
                u.w = pk1(xs[3 * 4 + jj]);
                *reinterpret_cast<ushort4*>(&xt[(n4 + jj) * 264 + c_base]) = u;
            }
        }
    }
    __syncthreads();
    int w = t >> 6, lane = t & 63, l15 = lane & 15, q = lane >> 4;
    floatx4 acc[6];
#pragma unroll
    for (int k = 0; k < 6; k++) acc[k] = (floatx4){0.f, 0.f, 0.f, 0.f};
#pragma unroll
    for (int ks = 0; ks < 8; ks++) {
        short8 bfrag = load_frag(&xt[(w * 16 + l15) * 264 + ks * 32 + q * 8]);
#pragma unroll
        for (int ot = 0; ot < 6; ot++) {
            short8 afrag = load_frag(&W96[(size_t)(ot * 16 + l15) * CC + ks * 32 + q * 8]);
            acc[ot] = __builtin_amdgcn_mfma_f32_16x16x32_bf16(afrag, bfrag, acc[ot], 0, 0, 0);
        }
    }
    int n = n0 + w * 16 + l15;
    // Q, K: row layout [n][32]
#pragma unroll
    for (int ot = 0; ot < 4; ot++) {
        const float* bias = (ot < 2) ? bq : bk;
        ushort* dst = (ot < 2) ? Qt : Kt;
        int o0 = (ot & 1) * 16 + q * 4;
        float4 b4 = *reinterpret_cast<const float4*>(bias + o0);
        float sc = (ot < 2) ? LOG2E : 1.0f;
        ushort4 pk;
        pk.x = bf16r(acc[ot][0] + b4.x * sc);
        pk.y = bf16r(acc[ot][1] + b4.y * sc);
        pk.z = bf16r(acc[ot][2] + b4.z * sc);
        pk.w = bf16r(acc[ot][3] + b4.w * sc);
        *reinterpret_cast<ushort4*>(&dst[((size_t)b * NN + n) * CP + o0]) = pk;
    }
    // V: transposed layout [c][n], scalar coalesced stores
#pragma unroll
    for (int ot = 4; ot < 6; ot++) {
        int o0 = ((ot - 4) & 1) * 16 + q * 4;
        float4 b4 = *reinterpret_cast<const float4*>(bv + o0);
        const float* av = reinterpret_cast<const float*>(&acc[ot]);
        const float* bvv = reinterpret_cast<const float*>(&b4);
#pragma unroll
        for (int r = 0; r < 4; r++) {
            Vp[((size_t)b * CP + o0 + r) * NN + n] = bf16r(av[r] + bvv[r]);
        }
    }
}

// ---------------- Kernel 2: pass A — partial row sums of 2^(S') over m-halves.
// grid 1024 = ((b*64 + jt)*2 + mq). Wave w: private 512-m range, 8 chunks of 64 m,
// per-wave LDS double-buffer pipeline (no barriers in K-loop). ----------------
__global__ __launch_bounds__(256, 4) void passA_kernel(
    const ushort* __restrict__ Qt, const ushort* __restrict__ Kt, float* __restrict__ Fp) {
    __shared__ __align__(16) ushort smem[20480];  // 40960 B: 4 waves x dbuf x (64 rows x 40)
    int bid = blockIdx.x;
    int mq = bid & 1, jt = (bid >> 1) & 63, b = bid >> 7;
    int w = threadIdx.x >> 6, lane = threadIdx.x & 63;
    int l15 = lane & 15, q = lane >> 4;

    short8 af[4];
#pragma unroll
    for (int js = 0; js < 4; js++)
        af[js] = load_frag(&Qt[((size_t)b * NN + jt * 64 + js * 16 + l15) * CP + q * 8]);

    floatx4 lacc[4];
#pragma unroll
    for (int js = 0; js < 4; js++) lacc[js] = (floatx4){0.f, 0.f, 0.f, 0.f};

    const ushort* Kb = Kt + (size_t)b * NN * CP;
    int mbase = mq * 2048 + w * 512;
    ushort* wbase = smem + w * 5120;  // per-wave 10240B
    int r1 = lane >> 2, p8 = (lane & 3) * 8;

    // prologue: stage chunk 0 into buf0
    {
        int m0 = mbase;
#pragma unroll
        for (int s = 0; s < 4; s++) {
            int row = r1 + 16 * s;
            intx4 v = *reinterpret_cast<const intx4*>(Kb + (size_t)(m0 + row) * CP + p8);
            *reinterpret_cast<intx4*>(wbase + row * 40 + p8) = v;
        }
    }

#pragma unroll 2
    for (int t = 0; t < 8; t++) {
        int mn = mbase + ((t + 1) & 7) * 64;
        intx4 nk[4];
#pragma unroll
        for (int s = 0; s < 4; s++)
            nk[s] = *reinterpret_cast<const intx4*>(Kb + (size_t)(mn + r1 + 16 * s) * CP + p8);

        ushort* cb = wbase + (t & 1) * 2560;
#pragma unroll
        for (int ms = 0; ms < 4; ms++) {
            short8 bf = load_frag(cb + (ms * 16 + l15) * 40 + q * 8);
            floatx4 z = (floatx4){0.f, 0.f, 0.f, 0.f};
#pragma unroll
            for (int js = 0; js < 4; js++) {
                floatx4 s = __builtin_amdgcn_mfma_f32_16x16x32_bf16(af[js], bf, z, 0, 0, 0);
                lacc[js][0] += fexp2(s[0]);
                lacc[js][1] += fexp2(s[1]);
                lacc[js][2] += fexp2(s[2]);
                lacc[js][3] += fexp2(s[3]);
            }
        }
        ushort* nb = wbase + ((t + 1) & 1) * 2560;
#pragma unroll
        for (int s = 0; s < 4; s++)
            *reinterpret_cast<intx4*>(nb + (r1 + 16 * s) * 40 + p8) = nk[s];
    }

    // reduce 16 m-columns within each quad-group
#pragma unroll
    for (int js = 0; js < 4; js++) {
#pragma unroll
        for (int d = 1; d < 16; d <<= 1) {
            lacc[js][0] += __shfl_xor(lacc[js][0], d, 64);
            lacc[js][1] += __shfl_xor(lacc[js][1], d, 64);
            lacc[js][2] += __shfl_xor(lacc[js][2], d, 64);
            lacc[js][3] += __shfl_xor(lacc[js][3], d, 64);
        }
    }
    __syncthreads();  // pipeline LDS dead; reuse as red[4][64]
    float* red = reinterpret_cast<float*>(smem);
    if (l15 == 0) {
#pragma unroll
        for (int js = 0; js < 4; js++) {
#pragma unroll
            for (int r = 0; r < 4; r++) red[w * 64 + js * 16 + q * 4 + r] = lacc[js][r];
        }
    }
    __syncthreads();
    int t = threadIdx.x;
    if (t < 64) {
        float s = red[t] + red[64 + t] + red[128 + t] + red[192 + t];
        Fp[((size_t)mq * NB + b) * NN + jt * 64 + t] = s;
    }
}

// ---------------- Kernel 3: fold — elementwise Vp[c][n] *= 1/sum (no transpose) ----------------
__global__ __launch_bounds__(256) void fold_kernel(
    ushort* __restrict__ Vp, const float* __restrict__ Fp) {
    const size_t PL = (size_t)NB * NN;
    int b = blockIdx.x >> 4, sl = blockIdx.x & 15;
    int t = threadIdx.x;
    int nn = sl * 256 + (t & 31) * 8;
    int cg = t >> 5;  // 0..7 -> 4 c rows each
    size_t bn = (size_t)b * NN + nn;
    float f[8];
#pragma unroll
    for (int e = 0; e < 8; e++) f[e] = 1.0f / (Fp[bn + e] + Fp[PL + bn + e]);
#pragma unroll
    for (int r = 0; r < 4; r++) {
        int c = cg * 4 + r;
        ushort* p = Vp + ((size_t)b * CP + c) * NN + nn;
        intx4 raw = *reinterpret_cast<const intx4*>(p);
        const ushort* us = reinterpret_cast<const ushort*>(&raw);
        ushort o[8];
#pragma unroll
        for (int e = 0; e < 8; e++) o[e] = pk1(bf2f(us[e]) * f[e]);
        *reinterpret_cast<intx4*>(p) = *reinterpret_cast<intx4*>(o);
    }
}

// ---------------- Kernel 4: pass B — O[32c][32i] over all j; per-wave LDS dbuf pipeline
// (no K-loop barriers); merged partials; fused MFMA back-proj + bias + residual.
// grid 1024 = b(8) x it(128). ----------------
__global__ __launch_bounds__(256, 4) void passB_kernel(
    const ushort* __restrict__ Qt, const ushort* __restrict__ Kt, const ushort* __restrict__ Vp,
    const ushort* __restrict__ W2b, const float* __restrict__ bb, const float* __restrict__ x,
    float* __restrict__ out) {
    __shared__ __align__(16) ushort smem[20480];  // 40960 B: 4 waves x dbuf x (Q 32x40 + V 32x40)

    int bid = blockIdx.x;
    int it = bid & 127, b = bid >> 7;
    int w = threadIdx.x >> 6, lane = threadIdx.x & 63;
    int l15 = lane & 15, q = lane >> 4;
    int i0 = it * 32;

    short8 kf0 = load_frag(&Kt[((size_t)b * NN + i0 + l15) * CP + q * 8]);
    short8 kf1 = load_frag(&Kt[((size_t)b * NN + i0 + 16 + l15) * CP + q * 8]);

    floatx4 acc00 = (floatx4){0.f, 0.f, 0.f, 0.f};
    floatx4 acc10 = (floatx4){0.f, 0.f, 0.f, 0.f};
    floatx4 acc01 = (floatx4){0.f, 0.f, 0.f, 0.f};
    floatx4 acc11 = (floatx4){0.f, 0.f, 0.f, 0.f};

    int qrow = (l15 >> 2) * 8 + (l15 & 3);  // perm: C-layout of S == B-frag layout of PV
    const ushort* Qb = Qt + (size_t)b * NN * CP;
    const ushort* Vb = Vp + (size_t)b * CP * NN;
    ushort* wbase = smem + w * 5120;  // per-wave 10240B: [buf][Q 1280 ush | V 1280 ush]
    int r1 = lane >> 2, p8 = (lane & 3) * 8;

    // prologue: stage chunk 0 (jb = w) into buf0
    {
        int j0 = w * 32;
        intx4 q1 = *reinterpret_cast<const intx4*>(Qb + (size_t)(j0 + r1) * CP + p8);
        intx4 q2 = *reinterpret_cast<const intx4*>(Qb + (size_t)(j0 + r1 + 16) * CP + p8);
        intx4 v1 = *reinterpret_cast<const intx4*>(Vb + (size_t)r1 * NN + j0 + p8);
        intx4 v2 = *reinterpret_cast<const intx4*>(Vb + (size_t)(r1 + 16) * NN + j0 + p8);
        *reinterpret_cast<intx4*>(wbase + r1 * 40 + p8) = q1;
        *reinterpret_cast<intx4*>(wbase + (r1 + 16) * 40 + p8) = q2;
        *reinterpret_cast<intx4*>(wbase + 1280 + r1 * 40 + p8) = v1;
        *reinterpret_cast<intx4*>(wbase + 1280 + (r1 + 16) * 40 + p8) = v2;
    }

#pragma unroll 2
    for (int t = 0; t < 32; t++) {
        int jn = ((w + (t + 1) * 4) & 127) * 32;
        intx4 nq1 = *reinterpret_cast<const intx4*>(Qb + (size_t)(jn + r1) * CP + p8);
        intx4 nq2 = *reinterpret_cast<const intx4*>(Qb + (size_t)(jn + r1 + 16) * CP + p8);
        intx4 nv1 = *reinterpret_cast<const intx4*>(Vb + (size_t)r1 * NN + jn + p8);
        intx4 nv2 = *reinterpret_cast<const intx4*>(Vb + (size_t)(r1 + 16) * NN + jn + p8);

        ushort* cb = wbase + (t & 1) * 2560;
        short8 a0 = load_frag(cb + qrow * 40 + q * 8);
        short8 a1 = load_frag(cb + (qrow + 4) * 40 + q * 8);
        short8 va0 = load_frag(cb + 1280 + l15 * 40 + q * 8);
        short8 va1 = load_frag(cb + 1280 + (16 + l15) * 40 + q * 8);

        floatx4 z = (floatx4){0.f, 0.f, 0.f, 0.f};
        floatx4 s0A = __builtin_amdgcn_mfma_f32_16x16x32_bf16(a0, kf0, z, 0, 0, 0);
        floatx4 s1A = __builtin_amdgcn_mfma_f32_16x16x32_bf16(a1, kf0, z, 0, 0, 0);
        floatx4 s0B = __builtin_amdgcn_mfma_f32_16x16x32_bf16(a0, kf1, z, 0, 0, 0);
        floatx4 s1B = __builtin_amdgcn_mfma_f32_16x16x32_bf16(a1, kf1, z, 0, 0, 0);

        union { intx4 v; short8 s; } wa, wb2;
        wa.v.x = pk2(fexp2(s0A[0]), fexp2(s0A[1]));
        wa.v.y = pk2(fexp2(s0A[2]), fexp2(s0A[3]));
        wa.v.z = pk2(fexp2(s1A[0]), fexp2(s1A[1]));
        wa.v.w = pk2(fexp2(s1A[2]), fexp2(s1A[3]));
        wb2.v.x = pk2(fexp2(s0B[0]), fexp2(s0B[1]));
        wb2.v.y = pk2(fexp2(s0B[2]), fexp2(s0B[3]));
        wb2.v.z = pk2(fexp2(s1B[0]), fexp2(s1B[1]));
        wb2.v.w = pk2(fexp2(s1B[2]), fexp2(s1B[3]));

        acc00 = __builtin_amdgcn_mfma_f32_16x16x32_bf16(va0, wa.s, acc00, 0, 0, 0);
        acc10 = __builtin_amdgcn_mfma_f32_16x16x32_bf16(va1, wa.s, acc10, 0, 0, 0);
        acc01 = __builtin_amdgcn_mfma_f32_16x16x32_bf16(va0, wb2.s, acc01, 0, 0, 0);
        acc11 = __builtin_amdgcn_mfma_f32_16x16x32_bf16(va1, wb2.s, acc11, 0, 0, 0);

        ushort* nb = wbase + ((t + 1) & 1) * 2560;
        *reinterpret_cast<intx4*>(nb + r1 * 40 + p8) = nq1;
        *reinterpret_cast<intx4*>(nb + (r1 + 16) * 40 + p8) = nq2;
        *reinterpret_cast<intx4*>(nb + 1280 + r1 * 40 + p8) = nv1;
        *reinterpret_cast<intx4*>(nb + 1280 + (r1 + 16) * 40 + p8) = nv2;
    }

    // ---- merge 4 wave partials (reuse pipeline LDS): olds4[w][32 c][33] ----
    __syncthreads();
    float* olds4 = reinterpret_cast<float*>(smem);
    int mbase = w * (32 * 33);
#pragma unroll
    for (int r = 0; r < 4; r++) {
        olds4[mbase + (q * 4 + r) * 33 + l15] = acc00[r];
        olds4[mbase + (16 + q * 4 + r) * 33 + l15] = acc10[r];
        olds4[mbase + (q * 4 + r) * 33 + 16 + l15] = acc01[r];
        olds4[mbase + (16 + q * 4 + r) * 33 + 16 + l15] = acc11[r];
    }
    __syncthreads();

    // ---- epilogue: back[c,i] = Wb.O + bb + x ; wave w handles c in [w*64, w*64+64) ----
    short8 bfr[2];
#pragma unroll
    for (int s = 0; s < 2; s++) {
        float o8[8];
#pragma unroll
        for (int jj = 0; jj < 8; jj++) {
            int o = q * 8 + jj;
            int idx = o * 33 + s * 16 + l15;
            o8[jj] = olds4[idx] + olds4[1056 + idx] + olds4[2112 + idx] + olds4[3168 + idx];
        }
        union { intx4 v; short8 sh; } u;
        u.v.x = pk2(o8[0], o8[1]);
        u.v.y = pk2(o8[2], o8[3]);
        u.v.z = pk2(o8[4], o8[5]);
        u.v.w = pk2(o8[6], o8[7]);
        bfr[s] = u.sh;
    }
    int c0 = w * 64;
#pragma unroll
    for (int cs = 0; cs < 4; cs++) {
        short8 af = load_frag(&W2b[(size_t)(c0 + cs * 16 + l15) * CP + q * 8]);
#pragma unroll
        for (int s = 0; s < 2; s++) {
            floatx4 z = (floatx4){0.f, 0.f, 0.f, 0.f};
            floatx4 d = __builtin_amdgcn_mfma_f32_16x16x32_bf16(af, bfr[s], z, 0, 0, 0);
#pragma unroll
            for (int r = 0; r < 4; r++) {
                int c = c0 + cs * 16 + q * 4 + r;
                int i = i0 + s * 16 + l15;
                size_t idx = ((size_t)b * CC + c) * NN + i;
                out[idx] = d[r] + bb[c] + x[idx];
            }
        }
    }
}

extern "C" void kernel_launch(void* const* d_in, const int* in_sizes, int n_in,
                              void* d_out, int out_size, void* d_ws, size_t ws_size,
                              hipStream_t stream) {
    const float* x  = (const float*)d_in[0];
    const float* Wq = (const float*)d_in[1];
    const float* bq = (const float*)d_in[2];
    const float* Wk = (const float*)d_in[3];
    const float* bk = (const float*)d_in[4];
    const float* Wv = (const float*)d_in[5];
    const float* bv = (const float*)d_in[6];
    const float* Wb = (const float*)d_in[7];
    const float* bb = (const float*)d_in[8];
    float* out = (float*)d_out;

    char* ws = (char*)d_ws;
    ushort* Qt  = (ushort*)(ws);                                   // 0..2MB
    ushort* Kt  = (ushort*)(ws + (2u << 20));                      // 2..4MB
    ushort* Vp  = (ushort*)(ws + (4u << 20));                      // 4..6MB
    float*  Fp  = (float*) (ws + (6u << 20));                      // 6..6.25MB (2 planes)
    ushort* W96 = (ushort*)(ws + (6u << 20) + (1u << 19));         // 48KB
    ushort* W2b = (ushort*)(ws + (6u << 20) + (1u << 19) + (48u << 10));  // 16KB

    prep_w<<<128, 256, 0, stream>>>(Wq, Wk, Wv, Wb, W96, W2b);
    proj_kernel<<<512, 256, 0, stream>>>(x, W96, bq, bk, bv, Qt, Kt, Vp);
    passA_kernel<<<1024, 256, 0, stream>>>(Qt, Kt, Fp);
    fold_kernel<<<128, 256, 0, stream>>>(Vp, Fp);
    passB_kernel<<<1024, 256, 0, stream>>>(Qt, Kt, Vp, W2b, bb, x, out);
}